// Round 7
// baseline (30057.037 us; speedup 1.0000x reference)
//
#include <hip/hip_runtime.h>

// Problem constants
constexpr int nB = 32, nT = 4096, nK = 256, nTP = 1024;

__device__ __forceinline__ float sigmoidf_(float x) { return 1.f / (1.f + expf(-x)); }

typedef unsigned int u32x4 __attribute__((ext_vector_type(4)));

// write-through stores: sc0 sc1 -> visible at device coherence point (memory-side)
__device__ __forceinline__ void store_u32_wt(unsigned* p, unsigned v) {
  asm volatile("global_store_dword %0, %1, off sc0 sc1" :: "v"(p), "v"(v) : "memory");
}
__device__ __forceinline__ void store_f32_wt(float* p, float v) {
  asm volatile("global_store_dword %0, %1, off sc0 sc1" :: "v"(p), "v"(v) : "memory");
}

// cross-lane helpers: bit-identical replacements for __shfl_xor(x, m, 32)
// xor1 = quad_perm(1,0,3,2)=0xB1 ; xor2 = quad_perm(2,3,0,1)=0x4E ;
// xor8 = row_ror:8 = 0x128 ((l+8)%16 == l^8) ; xor4/xor16 via ds_swizzle BitMode.
__device__ __forceinline__ float dpp_xor1(float x) {
  return __int_as_float(__builtin_amdgcn_update_dpp(0, __float_as_int(x), 0xB1, 0xF, 0xF, true));
}
__device__ __forceinline__ float dpp_xor2(float x) {
  return __int_as_float(__builtin_amdgcn_update_dpp(0, __float_as_int(x), 0x4E, 0xF, 0xF, true));
}
__device__ __forceinline__ float dpp_xor8(float x) {
  return __int_as_float(__builtin_amdgcn_update_dpp(0, __float_as_int(x), 0x128, 0xF, 0xF, true));
}
__device__ __forceinline__ float swz_xor4(float x) {
  return __int_as_float(__builtin_amdgcn_ds_swizzle(__float_as_int(x), 0x101F));
}
__device__ __forceinline__ float swz_xor16(float x) {
  return __int_as_float(__builtin_amdgcn_ds_swizzle(__float_as_int(x), 0x401F));
}

// ---------------- tokenizer (unchanged, verified absmax 0) ----------------

__global__ __launch_bounds__(256) void k_mean(const float* __restrict__ x, float* __restrict__ sig) {
  int row = blockIdx.x * 4 + (threadIdx.x >> 6);
  int lane = threadIdx.x & 63;
  float v = x[(size_t)row * 64 + lane];
  #pragma unroll
  for (int off = 32; off > 0; off >>= 1) v += __shfl_down(v, off, 64);
  if (lane == 0) sig[row] = v * (1.0f / 64.0f);
}

__global__ __launch_bounds__(256) void k_conv1(const float* __restrict__ sig,
    const float* __restrict__ w1, const float* __restrict__ b1, float* __restrict__ h1) {
  int idx = blockIdx.x * 256 + threadIdx.x;
  int o = idx & 2047;
  int co = (idx >> 11) & 63;
  int b = idx >> 17;
  const float* s = sig + (size_t)b * nT;
  float acc = b1[co];
  int base = 2 * o - 1;
  #pragma unroll
  for (int j = 0; j < 4; j++) {
    int p = base + j;
    float sv = (p >= 0 && p < nT) ? s[p] : 0.f;
    acc = fmaf(w1[co * 4 + j], sv, acc);
  }
  h1[idx] = fmaxf(acc, 0.f);
}

__global__ __launch_bounds__(256) void k_conv2(const float* __restrict__ h1,
    const float* __restrict__ w2, const float* __restrict__ b2, float* __restrict__ h2) {
  int blk = blockIdx.x;
  int otile = blk & 3, co = (blk >> 2) & 63, b = blk >> 8;
  int o = otile * 256 + threadIdx.x;
  __shared__ float w[256];
  w[threadIdx.x] = w2[co * 256 + threadIdx.x];
  __syncthreads();
  const float* hin = h1 + (size_t)b * 64 * 2048;
  float acc = b2[co];
  int base = 2 * o - 1;
  for (int ci = 0; ci < 64; ci++) {
    const float* r = hin + ci * 2048;
    const float* wc = w + ci * 4;
    #pragma unroll
    for (int j = 0; j < 4; j++) {
      int p = base + j;
      float v = (p >= 0 && p < 2048) ? r[p] : 0.f;
      acc = fmaf(wc[j], v, acc);
    }
  }
  h2[((size_t)b * 64 + co) * 1024 + o] = fmaxf(acc, 0.f);
}

__global__ __launch_bounds__(256) void k_conv3(const float* __restrict__ h2,
    const float* __restrict__ w3, const float* __restrict__ b3, float* __restrict__ ze) {
  int blk = blockIdx.x;
  int otile = blk & 3, co = (blk >> 2) & 63, b = blk >> 8;
  int o = otile * 256 + threadIdx.x;
  __shared__ float w[192];
  if (threadIdx.x < 192) w[threadIdx.x] = w3[co * 192 + threadIdx.x];
  __syncthreads();
  const float* hin = h2 + (size_t)b * 64 * 1024;
  float acc = b3[co];
  for (int ci = 0; ci < 64; ci++) {
    const float* r = hin + ci * 1024;
    const float* wc = w + ci * 3;
    #pragma unroll
    for (int j = 0; j < 3; j++) {
      int p = o - 1 + j;
      float v = (p >= 0 && p < 1024) ? r[p] : 0.f;
      acc = fmaf(wc[j], v, acc);
    }
  }
  ze[((size_t)b * 64 + co) * 1024 + o] = acc;
}

__global__ __launch_bounds__(256) void k_cbnorm(const float* __restrict__ cb, float* __restrict__ cbn) {
  int k = threadIdx.x;
  const float4* c4 = (const float4*)(cb + (size_t)k * 64);
  float acc = 0.f;
  #pragma unroll
  for (int q = 0; q < 16; q++) {
    float4 e = c4[q];
    acc = fmaf(e.x, e.x, fmaf(e.y, e.y, fmaf(e.z, e.z, fmaf(e.w, e.w, acc))));
  }
  cbn[k] = acc;
}

__global__ __launch_bounds__(256) void k_vq(const float* __restrict__ ze,
    const float* __restrict__ cb, const float* __restrict__ cbn, float* __restrict__ zq) {
  __shared__ float scb[nK * 64];
  for (int i = threadIdx.x; i < nK * 64; i += 256) scb[i] = cb[i];
  __syncthreads();
  int g = blockIdx.x * 256 + threadIdx.x;
  int b = g >> 10, o = g & 1023;
  const float* zb = ze + (size_t)b * 64 * 1024 + o;
  float z[64];
  #pragma unroll
  for (int d = 0; d < 64; d++) z[d] = zb[(size_t)d * 1024];
  float best = 3.4e38f; int bi = 0;
  for (int k = 0; k < nK; k++) {
    const float4* ck = (const float4*)(scb + k * 64);
    float dot = 0.f;
    #pragma unroll
    for (int q = 0; q < 16; q++) {
      float4 c4 = ck[q];
      dot = fmaf(c4.x, z[4 * q + 0], dot);
      dot = fmaf(c4.y, z[4 * q + 1], dot);
      dot = fmaf(c4.z, z[4 * q + 2], dot);
      dot = fmaf(c4.w, z[4 * q + 3], dot);
    }
    float s = cbn[k] - 2.f * dot;
    if (s < best) { best = s; bi = k; }
  }
  float4* zo4 = (float4*)(zq + (size_t)g * 64);
  const float4* cbest = (const float4*)(scb + bi * 64);
  #pragma unroll
  for (int q = 0; q < 16; q++) zo4[q] = cbest[q];
}

// transpose zq [b][t][d] -> zqT [t][d][b]
__global__ __launch_bounds__(256) void k_zqt(const float* __restrict__ zq, float* __restrict__ zqT) {
  int t = blockIdx.x;
  for (int o = threadIdx.x; o < 2048; o += 256) {
    int d = o >> 5, b = o & 31;
    zqT[(size_t)t * 2048 + o] = zq[((size_t)b * nTP + t) * 64 + d];
  }
}

// ---------------- persistent fused 2-layer LSTM + head ----------------
// Round-13: LDS-pipe offload + unified L1 + single staging exposure.
// r12 (-7.5%) validated in-phase stalls as the axis; counters showed the LDS
// pipe as the loaded serial resource (160 ds_swizzle + 48 b128/thread/step;
// conflicts 4.25e8) plus L1's divergent double-issue and a mid-phase MALL
// exposure for the h1 register cluster. Changes (all bit-identical math):
//  (1) shuffle rounds m=1,2,8 -> VALU DPP (quad_perm/row_ror); m=4,16 stay
//      ds_swizzle. -96 LDS ops/thread/step.
//  (2) h1[t-2] staged into LDS alongside h0[t-1]: ONE MALL exposure per step
//      for all state; L1 becomes non-divergent pointer-select (h1s/h0s);
//      head reads h1s from LDS.
//  (3) wB weights -> 128 VGPRs/thread (frees 37KB LDS so h0s+h1s fit:
//      ~154KB); removes 32 ds_read_b128/thread/step. launch_bounds(512,2).
//  (4) per-pattern swizzle keys: h0s ^((lin>>9)&7)<<2, h1s ^((lin>>10)&7)<<2
//      -> balanced banks for stage-write/L0/L1/head reads.

__global__ __launch_bounds__(512, 2) void k_lstm(
    const float* __restrict__ zqT,
    const float* __restrict__ wih0, const float* __restrict__ whh0, const float* __restrict__ bl0,
    const float* __restrict__ wih1, const float* __restrict__ whh1, const float* __restrict__ bl1,
    const float* __restrict__ wout, const float* __restrict__ bout,
    float* __restrict__ st, float* __restrict__ out)
{
  __shared__ float wAh[2][4][32][20];
  __shared__ float wAz[2][4][64];
  __shared__ float wHd[2][512];
  __shared__ float bHd[2];
  __shared__ float h0s[16384];   // staged h0[t-1], swizzle key (lin>>9)&7
  __shared__ float h1s[16384];   // staged h1[t-2], swizzle key (lin>>10)&7

  float* h0T = st;                          // [2][512][32]
  float* h1T = st + 32768;                  // [2][512][32]
  unsigned* flags = (unsigned*)(st + 65536); // [256]

  const int blk = blockIdx.x;
  const int tid = threadIdx.x;
  const int dim = tid >> 8;
  const int bg  = (tid >> 5) & 7;
  const int c   = tid & 31;
  const int b0  = bg * 4;
  const int j   = 2 * blk + dim;

  // ---- L1 weights into VGPRs (wbr[g][s] = wB[dim][g][c][s*4..s*4+3]) ----
  float4 wbr[4][8];
  {
    const float* wsrc = (c < 16) ? whh1 : wih1;
    #pragma unroll
    for (int g = 0; g < 4; g++) {
      const float* rw = wsrc + (size_t)(g * 512 + j) * 512 + (c & 15) * 32;
      #pragma unroll
      for (int s = 0; s < 8; s++) wbr[g][s] = *(const float4*)(rw + s * 4);
    }
  }

  // ---- stage L0 weights into LDS ----
  for (int idx = tid; idx < 2 * 4 * 32 * 16; idx += 512) {
    int k = idx & 15, cc = (idx >> 4) & 31, gg = (idx >> 9) & 3, dd = idx >> 11;
    wAh[dd][gg][cc][k] = whh0[(size_t)(gg * 512 + 2 * blk + dd) * 512 + cc * 16 + k];
  }
  if (tid < 512) {
    int d = tid & 63, gg = (tid >> 6) & 3, dd = tid >> 8;
    wAz[dd][gg][d] = wih0[(size_t)(gg * 512 + 2 * blk + dd) * 64 + d];
  }
  if (blk < 96) {
    for (int idx = tid; idx < 1024; idx += 512) {
      int q = idx >> 9, i = idx & 511;
      int p = blk * 2 + q;
      wHd[q][i] = wout[(size_t)(p >> 5) * 512 + i];
      if (i == 0) bHd[q] = bout[p >> 5];
    }
  }
  float bA[4], bB4[4];
  #pragma unroll
  for (int g = 0; g < 4; g++) { bA[g] = bl0[g * 512 + j]; bB4[g] = bl1[g * 512 + j]; }
  float creg0 = 0.f, creg1 = 0.f;   // cell state for (j, b0+c), lanes c<4 only
  __syncthreads();

  // per-lane swizzled LDS bases
  const float* h0vL0 = h0s + ((c * 512 + b0) ^ ((c & 7) << 2));   // L0: rows c*16+idx
  const int cp = c & 15;
  // L1 unified: c<16 -> h1s rows c*32+k (key c&7 const); c>=16 -> h0s rows cp*32+k
  // (key (2cp + k>>4)&7 -> two bases for k<16 / k>=16)
  const float* l1bufc = (c < 16) ? h1s : h0s;
  const unsigned keyA = (c < 16) ? (unsigned)(c & 7) : (unsigned)((2 * cp) & 7);
  const unsigned keyB = (c < 16) ? (unsigned)(c & 7) : (unsigned)((2 * cp + 1) & 7);
  const float* vsA = l1bufc + ((cp * 1024 + b0) ^ (keyA << 2));
  const float* vsB = l1bufc + ((cp * 1024 + 512 + b0) ^ (keyB << 2));

  for (int t = 0; t <= nTP + 1; t++) {
    // ---- stage h0[t-1] and h1[t-2] into swizzled LDS (one exposure) ----
    {
      const float* src0 = h0T + (t & 1) * 16384;
      const float* src1 = h1T + ((t + 1) & 1) * 16384;   // (t-1)&1 == (t+1)&1
      #pragma unroll
      for (int q = 0; q < 8; q++) {
        int o = (q * 512 + tid) * 4;
        float4 a  = *(const float4*)(src0 + o);
        float4 bq = *(const float4*)(src1 + o);
        *(float4*)&h0s[o ^ (((o >> 9) & 7) << 2)]  = a;
        *(float4*)&h1s[o ^ (((o >> 10) & 7) << 2)] = bq;
      }
      __syncthreads();
    }

    // ---- L0 step t: read h0s + wAh(LDS) + zqT, write h0T global-wt ----
    if (t < nTP) {
      float acc[16];
      #pragma unroll
      for (int r = 0; r < 16; r++) acc[r] = 0.f;
      {
        #pragma unroll
        for (int s = 0; s < 4; s++) {
          float4 v0 = *(const float4*)(h0vL0 + (s * 4 + 0) * 32);
          float4 v1 = *(const float4*)(h0vL0 + (s * 4 + 1) * 32);
          float4 v2 = *(const float4*)(h0vL0 + (s * 4 + 2) * 32);
          float4 v3 = *(const float4*)(h0vL0 + (s * 4 + 3) * 32);
          #pragma unroll
          for (int g = 0; g < 4; g++) {
            float4 w = *(const float4*)&wAh[dim][g][c][s * 4];
            float* a = acc + g * 4;
            a[0]=fmaf(w.x,v0.x,a[0]); a[0]=fmaf(w.y,v1.x,a[0]); a[0]=fmaf(w.z,v2.x,a[0]); a[0]=fmaf(w.w,v3.x,a[0]);
            a[1]=fmaf(w.x,v0.y,a[1]); a[1]=fmaf(w.y,v1.y,a[1]); a[1]=fmaf(w.z,v2.y,a[1]); a[1]=fmaf(w.w,v3.y,a[1]);
            a[2]=fmaf(w.x,v0.z,a[2]); a[2]=fmaf(w.y,v1.z,a[2]); a[2]=fmaf(w.z,v2.z,a[2]); a[2]=fmaf(w.w,v3.z,a[2]);
            a[3]=fmaf(w.x,v0.w,a[3]); a[3]=fmaf(w.y,v1.w,a[3]); a[3]=fmaf(w.z,v2.w,a[3]); a[3]=fmaf(w.w,v3.w,a[3]);
          }
        }
      }
      {
        const float* zt = zqT + (size_t)t * 2048 + b0;
        float4 u0 = *(const float4*)(zt + (c * 2 + 0) * 32);
        float4 u1 = *(const float4*)(zt + (c * 2 + 1) * 32);
        #pragma unroll
        for (int g = 0; g < 4; g++) {
          float wx = wAz[dim][g][c * 2 + 0], wy = wAz[dim][g][c * 2 + 1];
          float* a = acc + g * 4;
          a[0]=fmaf(wx,u0.x,a[0]); a[0]=fmaf(wy,u1.x,a[0]);
          a[1]=fmaf(wx,u0.y,a[1]); a[1]=fmaf(wy,u1.y,a[1]);
          a[2]=fmaf(wx,u0.z,a[2]); a[2]=fmaf(wy,u1.z,a[2]);
          a[3]=fmaf(wx,u0.w,a[3]); a[3]=fmaf(wy,u1.w,a[3]);
        }
      }
      // reduce: same tree order m = 1,2,4,8,16 (bit-identical)
      #pragma unroll
      for (int r = 0; r < 16; r++) acc[r] += dpp_xor1(acc[r]);
      #pragma unroll
      for (int r = 0; r < 16; r++) acc[r] += dpp_xor2(acc[r]);
      #pragma unroll
      for (int r = 0; r < 16; r++) acc[r] += swz_xor4(acc[r]);
      #pragma unroll
      for (int r = 0; r < 16; r++) acc[r] += dpp_xor8(acc[r]);
      #pragma unroll
      for (int r = 0; r < 16; r++) acc[r] += swz_xor16(acc[r]);
      if (c < 4) {
        int b = b0 + c;
        float gi = sigmoidf_(acc[0 * 4 + c] + bA[0]);
        float gf = sigmoidf_(acc[1 * 4 + c] + bA[1]);
        float gg = tanhf    (acc[2 * 4 + c] + bA[2]);
        float go = sigmoidf_(acc[3 * 4 + c] + bA[3]);
        float cn = fmaf(gf, creg0, gi * gg);
        creg0 = cn;
        store_f32_wt(h0T + ((t + 1) & 1) * 16384 + j * 32 + b, go * tanhf(cn));
      }
    }

    // ---- L1 step t-1: unified LDS reads (h1s for c<16, h0s for c>=16), wB in regs ----
    if (t >= 1 && t <= nTP) {
      float acc[16];
      #pragma unroll
      for (int r = 0; r < 16; r++) acc[r] = 0.f;
      #pragma unroll
      for (int s = 0; s < 8; s++) {
        const float* vb = (s < 4) ? vsA : vsB;
        const int k0 = (s < 4) ? s * 4 : (s - 4) * 4;
        float4 v0 = *(const float4*)(vb + (k0 + 0) * 32);
        float4 v1 = *(const float4*)(vb + (k0 + 1) * 32);
        float4 v2 = *(const float4*)(vb + (k0 + 2) * 32);
        float4 v3 = *(const float4*)(vb + (k0 + 3) * 32);
        #pragma unroll
        for (int g = 0; g < 4; g++) {
          float4 w = wbr[g][s];
          float* a = acc + g * 4;
          a[0]=fmaf(w.x,v0.x,a[0]); a[0]=fmaf(w.y,v1.x,a[0]); a[0]=fmaf(w.z,v2.x,a[0]); a[0]=fmaf(w.w,v3.x,a[0]);
          a[1]=fmaf(w.x,v0.y,a[1]); a[1]=fmaf(w.y,v1.y,a[1]); a[1]=fmaf(w.z,v2.y,a[1]); a[1]=fmaf(w.w,v3.y,a[1]);
          a[2]=fmaf(w.x,v0.z,a[2]); a[2]=fmaf(w.y,v1.z,a[2]); a[2]=fmaf(w.z,v2.z,a[2]); a[2]=fmaf(w.w,v3.z,a[2]);
          a[3]=fmaf(w.x,v0.w,a[3]); a[3]=fmaf(w.y,v1.w,a[3]); a[3]=fmaf(w.z,v2.w,a[3]); a[3]=fmaf(w.w,v3.w,a[3]);
        }
      }
      #pragma unroll
      for (int r = 0; r < 16; r++) acc[r] += dpp_xor1(acc[r]);
      #pragma unroll
      for (int r = 0; r < 16; r++) acc[r] += dpp_xor2(acc[r]);
      #pragma unroll
      for (int r = 0; r < 16; r++) acc[r] += swz_xor4(acc[r]);
      #pragma unroll
      for (int r = 0; r < 16; r++) acc[r] += dpp_xor8(acc[r]);
      #pragma unroll
      for (int r = 0; r < 16; r++) acc[r] += swz_xor16(acc[r]);
      if (c < 4) {
        int b = b0 + c;
        float gi = sigmoidf_(acc[0 * 4 + c] + bB4[0]);
        float gf = sigmoidf_(acc[1 * 4 + c] + bB4[1]);
        float gg = tanhf    (acc[2 * 4 + c] + bB4[2]);
        float go = sigmoidf_(acc[3 * 4 + c] + bB4[3]);
        float cn = fmaf(gf, creg1, gi * gg);
        creg1 = cn;
        store_f32_wt(h1T + (t & 1) * 16384 + j * 32 + b, go * tanhf(cn));
      }
    }

    // drain this wave's loads and write-through stores, then block-wide rendezvous
    asm volatile("s_waitcnt vmcnt(0)" ::: "memory");
    __syncthreads();

    // ---- arrival flag (all waves drained at this point) ----
    if (t <= nTP && tid == 0) store_u32_wt(flags + blk, (unsigned)(t + 1));

    // ---- head for step t-2 on wave 1 (reads h1s LDS), overlapping barrier wait ----
    // STANDALONE guard: must also run at t == nTP+1 (emits output step 1023).
    if (t >= 2 && blk < 96 && tid >= 64 && tid < 80) {
      int q = (tid >> 3) & 1, l = tid & 7;
      int p = blk * 2 + q;
      int b = p & 31;
      int base = l * 2048 + b;
      const float* hA = h1s + (base ^ (((2 * l) & 7) << 2));            // rows l*64+m, m<32
      const float* hB = h1s + ((base + 1024) ^ (((2 * l + 1) & 7) << 2)); // m>=32
      float a = 0.f;
      #pragma unroll 8
      for (int m = 0; m < 32; m++) a = fmaf(wHd[q][l * 64 + m], hA[m * 32], a);
      #pragma unroll 8
      for (int m = 0; m < 32; m++) a = fmaf(wHd[q][l * 64 + 32 + m], hB[m * 32], a);
      a += __shfl_down(a, 4, 8);
      a += __shfl_down(a, 2, 8);
      a += __shfl_down(a, 1, 8);
      if (l == 0) out[((size_t)b * nTP + (t - 2)) * 6 + (p >> 5)] = a + bHd[q];
    }

    // ---- flat barrier: every block's wave 0 polls all 256 flags ----
    if (t <= nTP) {
      unsigned tgt = (unsigned)(t + 1);
      if (tid < 64) {
        const u32x4* fp = (const u32x4*)flags + tid;
        for (;;) {
          u32x4 f;
          asm volatile("global_load_dwordx4 %0, %1, off sc0 sc1\n\ts_waitcnt vmcnt(0)"
                       : "=&v"(f) : "v"(fp) : "memory");
          bool ok = (f.x >= tgt) && (f.y >= tgt) && (f.z >= tgt) && (f.w >= tgt);
          if (__all(ok)) break;
          __builtin_amdgcn_s_sleep(1);
        }
        __builtin_amdgcn_fence(__ATOMIC_ACQUIRE, "agent");  // buffer_inv
      }
      __syncthreads();
    }
  }
}

// ---------------- launch ----------------

extern "C" void kernel_launch(void* const* d_in, const int* in_sizes, int n_in,
                              void* d_out, int out_size, void* d_ws, size_t ws_size,
                              hipStream_t stream) {
  (void)in_sizes; (void)n_in; (void)out_size; (void)ws_size;
  const float* x    = (const float*)d_in[0];
  const float* w1   = (const float*)d_in[1];
  const float* b1   = (const float*)d_in[2];
  const float* w2   = (const float*)d_in[3];
  const float* b2   = (const float*)d_in[4];
  const float* w3   = (const float*)d_in[5];
  const float* b3   = (const float*)d_in[6];
  const float* cb   = (const float*)d_in[7];
  const float* wih0 = (const float*)d_in[8];
  const float* whh0 = (const float*)d_in[9];
  const float* bl0  = (const float*)d_in[10];
  const float* wih1 = (const float*)d_in[11];
  const float* whh1 = (const float*)d_in[12];
  const float* bl1  = (const float*)d_in[13];
  const float* wout = (const float*)d_in[14];
  const float* bout = (const float*)d_in[15];
  float* out = (float*)d_out;

  float* ws  = (float*)d_ws;
  // region reuse: st+flags overlaps sig (dead after conv1); zqT overlaps h1c (dead after conv2)
  float* sig = ws;                 // 131072 floats (later: h0T/h1T 65536 + flags)
  float* h1c = sig + 131072;       // 4194304  [32][64][2048] (later: zqT, 2097152)
  float* h2c = h1c + 4194304;      // 2097152  [32][64][1024]
  float* ze  = h2c + 2097152;      // 2097152  [32][64][1024]
  float* zq  = ze  + 2097152;      // 2097152  [32*1024][64]
  float* cbn = zq  + 2097152;      // 256
  float* stp = ws;                 // h0T[2][512][32], h1T[2][512][32], flags[256]
  float* zqT = h1c;                // 2097152  [1024][64][32]

  k_mean <<<32768, 256, 0, stream>>>(x, sig);
  k_conv1<<<16384, 256, 0, stream>>>(sig, w1, b1, h1c);
  hipMemsetAsync(stp, 0, (65536 + 1024) * sizeof(float), stream);  // state + flags
  k_conv2<<<8192, 256, 0, stream>>>(h1c, w2, b2, h2c);
  k_conv3<<<8192, 256, 0, stream>>>(h2c, w3, b3, ze);
  k_cbnorm<<<1, 256, 0, stream>>>(cb, cbn);
  k_vq   <<<128, 256, 0, stream>>>(ze, cb, cbn, zq);
  k_zqt  <<<1024, 256, 0, stream>>>(zq, zqT);   // h1c dead now; write zqT over it

  void* kargs[] = { (void*)&zqT, (void*)&wih0, (void*)&whh0, (void*)&bl0,
                    (void*)&wih1, (void*)&whh1, (void*)&bl1,
                    (void*)&wout, (void*)&bout, (void*)&stp, (void*)&out };
  hipLaunchCooperativeKernel((void*)k_lstm, dim3(256), dim3(512), kargs, 0, stream);
}

// Round 8
// 16538.815 us; speedup vs baseline: 1.8174x; 1.8174x over previous
//
#include <hip/hip_runtime.h>

// Problem constants
constexpr int nB = 32, nT = 4096, nK = 256, nTP = 1024;

__device__ __forceinline__ float sigmoidf_(float x) { return 1.f / (1.f + expf(-x)); }

typedef unsigned int u32x4 __attribute__((ext_vector_type(4)));

// write-through stores: sc0 sc1 -> visible at device coherence point (memory-side)
__device__ __forceinline__ void store_u32_wt(unsigned* p, unsigned v) {
  asm volatile("global_store_dword %0, %1, off sc0 sc1" :: "v"(p), "v"(v) : "memory");
}
__device__ __forceinline__ void store_f32_wt(float* p, float v) {
  asm volatile("global_store_dword %0, %1, off sc0 sc1" :: "v"(p), "v"(v) : "memory");
}

// cross-lane helpers: bit-identical replacements for __shfl_xor(x, m, 32)
// xor1 = quad_perm(1,0,3,2)=0xB1 ; xor2 = quad_perm(2,3,0,1)=0x4E ;
// xor8 = row_ror:8 = 0x128 ((l+8)%16 == l^8 within each 16-lane row) ;
// xor4/xor16 via ds_swizzle BitMode. Verified bit-identical on HW (r13 absmax 0.0).
__device__ __forceinline__ float dpp_xor1(float x) {
  return __int_as_float(__builtin_amdgcn_update_dpp(0, __float_as_int(x), 0xB1, 0xF, 0xF, true));
}
__device__ __forceinline__ float dpp_xor2(float x) {
  return __int_as_float(__builtin_amdgcn_update_dpp(0, __float_as_int(x), 0x4E, 0xF, 0xF, true));
}
__device__ __forceinline__ float dpp_xor8(float x) {
  return __int_as_float(__builtin_amdgcn_update_dpp(0, __float_as_int(x), 0x128, 0xF, 0xF, true));
}
__device__ __forceinline__ float swz_xor4(float x) {
  return __int_as_float(__builtin_amdgcn_ds_swizzle(__float_as_int(x), 0x101F));
}
__device__ __forceinline__ float swz_xor16(float x) {
  return __int_as_float(__builtin_amdgcn_ds_swizzle(__float_as_int(x), 0x401F));
}

// ---------------- tokenizer (unchanged, verified absmax 0) ----------------

__global__ __launch_bounds__(256) void k_mean(const float* __restrict__ x, float* __restrict__ sig) {
  int row = blockIdx.x * 4 + (threadIdx.x >> 6);
  int lane = threadIdx.x & 63;
  float v = x[(size_t)row * 64 + lane];
  #pragma unroll
  for (int off = 32; off > 0; off >>= 1) v += __shfl_down(v, off, 64);
  if (lane == 0) sig[row] = v * (1.0f / 64.0f);
}

__global__ __launch_bounds__(256) void k_conv1(const float* __restrict__ sig,
    const float* __restrict__ w1, const float* __restrict__ b1, float* __restrict__ h1) {
  int idx = blockIdx.x * 256 + threadIdx.x;
  int o = idx & 2047;
  int co = (idx >> 11) & 63;
  int b = idx >> 17;
  const float* s = sig + (size_t)b * nT;
  float acc = b1[co];
  int base = 2 * o - 1;
  #pragma unroll
  for (int j = 0; j < 4; j++) {
    int p = base + j;
    float sv = (p >= 0 && p < nT) ? s[p] : 0.f;
    acc = fmaf(w1[co * 4 + j], sv, acc);
  }
  h1[idx] = fmaxf(acc, 0.f);
}

__global__ __launch_bounds__(256) void k_conv2(const float* __restrict__ h1,
    const float* __restrict__ w2, const float* __restrict__ b2, float* __restrict__ h2) {
  int blk = blockIdx.x;
  int otile = blk & 3, co = (blk >> 2) & 63, b = blk >> 8;
  int o = otile * 256 + threadIdx.x;
  __shared__ float w[256];
  w[threadIdx.x] = w2[co * 256 + threadIdx.x];
  __syncthreads();
  const float* hin = h1 + (size_t)b * 64 * 2048;
  float acc = b2[co];
  int base = 2 * o - 1;
  for (int ci = 0; ci < 64; ci++) {
    const float* r = hin + ci * 2048;
    const float* wc = w + ci * 4;
    #pragma unroll
    for (int j = 0; j < 4; j++) {
      int p = base + j;
      float v = (p >= 0 && p < 2048) ? r[p] : 0.f;
      acc = fmaf(wc[j], v, acc);
    }
  }
  h2[((size_t)b * 64 + co) * 1024 + o] = fmaxf(acc, 0.f);
}

__global__ __launch_bounds__(256) void k_conv3(const float* __restrict__ h2,
    const float* __restrict__ w3, const float* __restrict__ b3, float* __restrict__ ze) {
  int blk = blockIdx.x;
  int otile = blk & 3, co = (blk >> 2) & 63, b = blk >> 8;
  int o = otile * 256 + threadIdx.x;
  __shared__ float w[192];
  if (threadIdx.x < 192) w[threadIdx.x] = w3[co * 192 + threadIdx.x];
  __syncthreads();
  const float* hin = h2 + (size_t)b * 64 * 1024;
  float acc = b3[co];
  for (int ci = 0; ci < 64; ci++) {
    const float* r = hin + ci * 1024;
    const float* wc = w + ci * 3;
    #pragma unroll
    for (int j = 0; j < 3; j++) {
      int p = o - 1 + j;
      float v = (p >= 0 && p < 1024) ? r[p] : 0.f;
      acc = fmaf(wc[j], v, acc);
    }
  }
  ze[((size_t)b * 64 + co) * 1024 + o] = acc;
}

__global__ __launch_bounds__(256) void k_cbnorm(const float* __restrict__ cb, float* __restrict__ cbn) {
  int k = threadIdx.x;
  const float4* c4 = (const float4*)(cb + (size_t)k * 64);
  float acc = 0.f;
  #pragma unroll
  for (int q = 0; q < 16; q++) {
    float4 e = c4[q];
    acc = fmaf(e.x, e.x, fmaf(e.y, e.y, fmaf(e.z, e.z, fmaf(e.w, e.w, acc))));
  }
  cbn[k] = acc;
}

__global__ __launch_bounds__(256) void k_vq(const float* __restrict__ ze,
    const float* __restrict__ cb, const float* __restrict__ cbn, float* __restrict__ zq) {
  __shared__ float scb[nK * 64];
  for (int i = threadIdx.x; i < nK * 64; i += 256) scb[i] = cb[i];
  __syncthreads();
  int g = blockIdx.x * 256 + threadIdx.x;
  int b = g >> 10, o = g & 1023;
  const float* zb = ze + (size_t)b * 64 * 1024 + o;
  float z[64];
  #pragma unroll
  for (int d = 0; d < 64; d++) z[d] = zb[(size_t)d * 1024];
  float best = 3.4e38f; int bi = 0;
  for (int k = 0; k < nK; k++) {
    const float4* ck = (const float4*)(scb + k * 64);
    float dot = 0.f;
    #pragma unroll
    for (int q = 0; q < 16; q++) {
      float4 c4 = ck[q];
      dot = fmaf(c4.x, z[4 * q + 0], dot);
      dot = fmaf(c4.y, z[4 * q + 1], dot);
      dot = fmaf(c4.z, z[4 * q + 2], dot);
      dot = fmaf(c4.w, z[4 * q + 3], dot);
    }
    float s = cbn[k] - 2.f * dot;
    if (s < best) { best = s; bi = k; }
  }
  float4* zo4 = (float4*)(zq + (size_t)g * 64);
  const float4* cbest = (const float4*)(scb + bi * 64);
  #pragma unroll
  for (int q = 0; q < 16; q++) zo4[q] = cbest[q];
}

// transpose zq [b][t][d] -> zqT [t][d][b]
__global__ __launch_bounds__(256) void k_zqt(const float* __restrict__ zq, float* __restrict__ zqT) {
  int t = blockIdx.x;
  for (int o = threadIdx.x; o < 2048; o += 256) {
    int d = o >> 5, b = o & 31;
    zqT[(size_t)t * 2048 + o] = zq[((size_t)b * nTP + t) * 64 + d];
  }
}

// ---------------- persistent fused 2-layer LSTM + head ----------------
// Round-14: strict A/B on the proven 18.4ms r12 kernel. Single change:
// shuffle-butterfly rounds m=1,2,8 -> VALU DPP (quad_perm 0xB1/0x4E,
// row_ror:8); m=4,16 stay ds_swizzle. Removes 96 of 160 LDS-pipe permute
// ops/thread/step. Everything else byte-identical to r12: h0s LDS staging
// w/ XOR swizzle, weights in LDS, L1 vbuf hoist (transient, spill-free),
// head from global h1T, flat-barrier protocol. r13's lesson applied: NO
// long-lived register arrays (wbr spilled -> 48GB/dispatch scratch traffic).

__global__ __launch_bounds__(512, 2) void k_lstm(
    const float* __restrict__ zqT,
    const float* __restrict__ wih0, const float* __restrict__ whh0, const float* __restrict__ bl0,
    const float* __restrict__ wih1, const float* __restrict__ whh1, const float* __restrict__ bl1,
    const float* __restrict__ wout, const float* __restrict__ bout,
    float* __restrict__ st, float* __restrict__ out)
{
  __shared__ float wB [2][4][32][36];
  __shared__ float wAh[2][4][32][20];
  __shared__ float wAz[2][4][64];
  __shared__ float wHd[2][512];
  __shared__ float bHd[2];
  __shared__ float h0s[16384];   // staged h0[t-1], XOR-swizzled [512][32]

  float* h0T = st;                          // [2][512][32]
  float* h1T = st + 32768;                  // [2][512][32]
  unsigned* flags = (unsigned*)(st + 65536); // [256]

  const int blk = blockIdx.x;
  const int tid = threadIdx.x;
  const int dim = tid >> 8;
  const int bg  = (tid >> 5) & 7;
  const int c   = tid & 31;
  const int b0  = bg * 4;
  const int j   = 2 * blk + dim;

  // ---- stage weights into LDS ----
  for (int idx = tid; idx < 2 * 4 * 32 * 32; idx += 512) {
    int k = idx & 31, cc = (idx >> 5) & 31, gg = (idx >> 10) & 3, dd = idx >> 12;
    int row = gg * 512 + 2 * blk + dd;
    float v = (cc < 16) ? whh1[(size_t)row * 512 + cc * 32 + k]
                        : wih1[(size_t)row * 512 + (cc - 16) * 32 + k];
    wB[dd][gg][cc][k] = v;
  }
  for (int idx = tid; idx < 2 * 4 * 32 * 16; idx += 512) {
    int k = idx & 15, cc = (idx >> 4) & 31, gg = (idx >> 9) & 3, dd = idx >> 11;
    wAh[dd][gg][cc][k] = whh0[(size_t)(gg * 512 + 2 * blk + dd) * 512 + cc * 16 + k];
  }
  if (tid < 512) {
    int d = tid & 63, gg = (tid >> 6) & 3, dd = tid >> 8;
    wAz[dd][gg][d] = wih0[(size_t)(gg * 512 + 2 * blk + dd) * 64 + d];
  }
  if (blk < 96) {
    for (int idx = tid; idx < 1024; idx += 512) {
      int q = idx >> 9, i = idx & 511;
      int p = blk * 2 + q;
      wHd[q][i] = wout[(size_t)(p >> 5) * 512 + i];
      if (i == 0) bHd[q] = bout[p >> 5];
    }
  }
  float bA[4], bB4[4];
  #pragma unroll
  for (int g = 0; g < 4; g++) { bA[g] = bl0[g * 512 + j]; bB4[g] = bl1[g * 512 + j]; }
  float creg0 = 0.f, creg1 = 0.f;   // cell state for (j, b0+c), lanes c<4 only
  __syncthreads();

  // per-lane swizzled LDS base pointers (swizzle bits 2-4; offsets use bits >=5)
  const float* h0vL0 = h0s + ((c * 512 + b0) ^ ((c & 7) << 2));
  const int cp = c - 16;
  const float* h0vA = h0s + (((cp < 0 ? 0 : cp) * 1024 + b0) ^ (((2 * (cp < 0 ? 0 : cp)) & 7) << 2));
  const float* h0vB = h0s + (((cp < 0 ? 0 : cp) * 1024 + 512 + b0) ^ (((2 * (cp < 0 ? 0 : cp) + 1) & 7) << 2));

  for (int t = 0; t <= nTP + 1; t++) {
    // ---- stage h0[t-1] (global, post-barrier-fresh) into swizzled LDS ----
    if (t <= nTP) {
      const float* src = h0T + (t & 1) * 16384;
      #pragma unroll
      for (int q = 0; q < 8; q++) {
        int lin = (q * 512 + tid) * 4;
        float4 v = *(const float4*)(src + lin);
        int phys = lin ^ (((lin >> 9) & 7) << 2);
        *(float4*)&h0s[phys] = v;
      }
      __syncthreads();
    }

    // ---- L0 step t (h from LDS) ----
    if (t < nTP) {
      float acc[16];
      #pragma unroll
      for (int r = 0; r < 16; r++) acc[r] = 0.f;
      {
        #pragma unroll
        for (int s = 0; s < 4; s++) {
          float4 v0 = *(const float4*)(h0vL0 + (s * 4 + 0) * 32);
          float4 v1 = *(const float4*)(h0vL0 + (s * 4 + 1) * 32);
          float4 v2 = *(const float4*)(h0vL0 + (s * 4 + 2) * 32);
          float4 v3 = *(const float4*)(h0vL0 + (s * 4 + 3) * 32);
          #pragma unroll
          for (int g = 0; g < 4; g++) {
            float4 w = *(const float4*)&wAh[dim][g][c][s * 4];
            float* a = acc + g * 4;
            a[0]=fmaf(w.x,v0.x,a[0]); a[0]=fmaf(w.y,v1.x,a[0]); a[0]=fmaf(w.z,v2.x,a[0]); a[0]=fmaf(w.w,v3.x,a[0]);
            a[1]=fmaf(w.x,v0.y,a[1]); a[1]=fmaf(w.y,v1.y,a[1]); a[1]=fmaf(w.z,v2.y,a[1]); a[1]=fmaf(w.w,v3.y,a[1]);
            a[2]=fmaf(w.x,v0.z,a[2]); a[2]=fmaf(w.y,v1.z,a[2]); a[2]=fmaf(w.z,v2.z,a[2]); a[2]=fmaf(w.w,v3.z,a[2]);
            a[3]=fmaf(w.x,v0.w,a[3]); a[3]=fmaf(w.y,v1.w,a[3]); a[3]=fmaf(w.z,v2.w,a[3]); a[3]=fmaf(w.w,v3.w,a[3]);
          }
        }
      }
      {
        const float* zt = zqT + (size_t)t * 2048 + b0;
        float4 u0 = *(const float4*)(zt + (c * 2 + 0) * 32);
        float4 u1 = *(const float4*)(zt + (c * 2 + 1) * 32);
        #pragma unroll
        for (int g = 0; g < 4; g++) {
          float wx = wAz[dim][g][c * 2 + 0], wy = wAz[dim][g][c * 2 + 1];
          float* a = acc + g * 4;
          a[0]=fmaf(wx,u0.x,a[0]); a[0]=fmaf(wy,u1.x,a[0]);
          a[1]=fmaf(wx,u0.y,a[1]); a[1]=fmaf(wy,u1.y,a[1]);
          a[2]=fmaf(wx,u0.z,a[2]); a[2]=fmaf(wy,u1.z,a[2]);
          a[3]=fmaf(wx,u0.w,a[3]); a[3]=fmaf(wy,u1.w,a[3]);
        }
      }
      // reduce: same tree order m = 1,2,4,8,16 (bit-identical)
      #pragma unroll
      for (int r = 0; r < 16; r++) acc[r] += dpp_xor1(acc[r]);
      #pragma unroll
      for (int r = 0; r < 16; r++) acc[r] += dpp_xor2(acc[r]);
      #pragma unroll
      for (int r = 0; r < 16; r++) acc[r] += swz_xor4(acc[r]);
      #pragma unroll
      for (int r = 0; r < 16; r++) acc[r] += dpp_xor8(acc[r]);
      #pragma unroll
      for (int r = 0; r < 16; r++) acc[r] += swz_xor16(acc[r]);
      if (c < 4) {
        int b = b0 + c;
        float gi = sigmoidf_(acc[0 * 4 + c] + bA[0]);
        float gf = sigmoidf_(acc[1 * 4 + c] + bA[1]);
        float gg = tanhf    (acc[2 * 4 + c] + bA[2]);
        float go = sigmoidf_(acc[3 * 4 + c] + bA[3]);
        float cn = fmaf(gf, creg0, gi * gg);
        creg0 = cn;
        store_f32_wt(h0T + ((t + 1) & 1) * 16384 + j * 32 + b, go * tanhf(cn));
      }
    }

    // ---- L1 step t-1: h1 (global, hoisted cluster) for c<16; h0 (LDS) for c>=16 ----
    if (t >= 1 && t <= nTP) {
      const float* h1p = h1T + ((t - 1) & 1) * 16384;
      float4 vbuf[32];
      if (c < 16) {
        const float* vg = h1p + c * 32 * 32 + b0;
        #pragma unroll
        for (int k = 0; k < 32; k++) vbuf[k] = *(const float4*)(vg + k * 32);
      } else {
        #pragma unroll
        for (int k = 0; k < 16; k++) vbuf[k] = *(const float4*)(h0vA + k * 32);
        #pragma unroll
        for (int k = 0; k < 16; k++) vbuf[16 + k] = *(const float4*)(h0vB + k * 32);
      }
      float acc[16];
      #pragma unroll
      for (int r = 0; r < 16; r++) acc[r] = 0.f;
      #pragma unroll
      for (int s = 0; s < 8; s++) {
        float4 v0 = vbuf[s * 4 + 0];
        float4 v1 = vbuf[s * 4 + 1];
        float4 v2 = vbuf[s * 4 + 2];
        float4 v3 = vbuf[s * 4 + 3];
        #pragma unroll
        for (int g = 0; g < 4; g++) {
          float4 w = *(const float4*)&wB[dim][g][c][s * 4];
          float* a = acc + g * 4;
          a[0]=fmaf(w.x,v0.x,a[0]); a[0]=fmaf(w.y,v1.x,a[0]); a[0]=fmaf(w.z,v2.x,a[0]); a[0]=fmaf(w.w,v3.x,a[0]);
          a[1]=fmaf(w.x,v0.y,a[1]); a[1]=fmaf(w.y,v1.y,a[1]); a[1]=fmaf(w.z,v2.y,a[1]); a[1]=fmaf(w.w,v3.y,a[1]);
          a[2]=fmaf(w.x,v0.z,a[2]); a[2]=fmaf(w.y,v1.z,a[2]); a[2]=fmaf(w.z,v2.z,a[2]); a[2]=fmaf(w.w,v3.z,a[2]);
          a[3]=fmaf(w.x,v0.w,a[3]); a[3]=fmaf(w.y,v1.w,a[3]); a[3]=fmaf(w.z,v2.w,a[3]); a[3]=fmaf(w.w,v3.w,a[3]);
        }
      }
      #pragma unroll
      for (int r = 0; r < 16; r++) acc[r] += dpp_xor1(acc[r]);
      #pragma unroll
      for (int r = 0; r < 16; r++) acc[r] += dpp_xor2(acc[r]);
      #pragma unroll
      for (int r = 0; r < 16; r++) acc[r] += swz_xor4(acc[r]);
      #pragma unroll
      for (int r = 0; r < 16; r++) acc[r] += dpp_xor8(acc[r]);
      #pragma unroll
      for (int r = 0; r < 16; r++) acc[r] += swz_xor16(acc[r]);
      if (c < 4) {
        int b = b0 + c;
        float gi = sigmoidf_(acc[0 * 4 + c] + bB4[0]);
        float gf = sigmoidf_(acc[1 * 4 + c] + bB4[1]);
        float gg = tanhf    (acc[2 * 4 + c] + bB4[2]);
        float go = sigmoidf_(acc[3 * 4 + c] + bB4[3]);
        float cn = fmaf(gf, creg1, gi * gg);
        creg1 = cn;
        store_f32_wt(h1T + (t & 1) * 16384 + j * 32 + b, go * tanhf(cn));
      }
    }

    // drain this wave's loads and write-through stores, then block-wide rendezvous
    asm volatile("s_waitcnt vmcnt(0)" ::: "memory");
    __syncthreads();

    // ---- arrival flag (all waves drained at this point) ----
    if (t <= nTP && tid == 0) store_u32_wt(flags + blk, (unsigned)(t + 1));

    // ---- head for step t-2 on wave 1, overlapping the barrier wait ----
    // STANDALONE guard: must also run at t == nTP+1 (emits output step 1023).
    if (t >= 2 && blk < 96 && tid >= 64 && tid < 80) {
      int q = (tid >> 3) & 1, l = tid & 7;
      int p = blk * 2 + q;
      int b = p & 31;
      const float* h1s = h1T + ((t - 1) & 1) * 16384;   // h1 step t-2 (covered by barrier t-1)
      float a = 0.f;
      #pragma unroll 8
      for (int m = 0; m < 64; m++) {
        int i = l * 64 + m;
        a = fmaf(wHd[q][i], h1s[i * 32 + b], a);
      }
      a += __shfl_down(a, 4, 8);
      a += __shfl_down(a, 2, 8);
      a += __shfl_down(a, 1, 8);
      if (l == 0) out[((size_t)b * nTP + (t - 2)) * 6 + (p >> 5)] = a + bHd[q];
    }

    // ---- flat barrier: every block's wave 0 polls all 256 flags ----
    if (t <= nTP) {
      unsigned tgt = (unsigned)(t + 1);
      if (tid < 64) {
        const u32x4* fp = (const u32x4*)flags + tid;
        for (;;) {
          u32x4 f;
          asm volatile("global_load_dwordx4 %0, %1, off sc0 sc1\n\ts_waitcnt vmcnt(0)"
                       : "=&v"(f) : "v"(fp) : "memory");
          bool ok = (f.x >= tgt) && (f.y >= tgt) && (f.z >= tgt) && (f.w >= tgt);
          if (__all(ok)) break;
          __builtin_amdgcn_s_sleep(1);
        }
        __builtin_amdgcn_fence(__ATOMIC_ACQUIRE, "agent");  // buffer_inv
      }
      __syncthreads();
    }
  }
}

// ---------------- launch ----------------

extern "C" void kernel_launch(void* const* d_in, const int* in_sizes, int n_in,
                              void* d_out, int out_size, void* d_ws, size_t ws_size,
                              hipStream_t stream) {
  (void)in_sizes; (void)n_in; (void)out_size; (void)ws_size;
  const float* x    = (const float*)d_in[0];
  const float* w1   = (const float*)d_in[1];
  const float* b1   = (const float*)d_in[2];
  const float* w2   = (const float*)d_in[3];
  const float* b2   = (const float*)d_in[4];
  const float* w3   = (const float*)d_in[5];
  const float* b3   = (const float*)d_in[6];
  const float* cb   = (const float*)d_in[7];
  const float* wih0 = (const float*)d_in[8];
  const float* whh0 = (const float*)d_in[9];
  const float* bl0  = (const float*)d_in[10];
  const float* wih1 = (const float*)d_in[11];
  const float* whh1 = (const float*)d_in[12];
  const float* bl1  = (const float*)d_in[13];
  const float* wout = (const float*)d_in[14];
  const float* bout = (const float*)d_in[15];
  float* out = (float*)d_out;

  float* ws  = (float*)d_ws;
  // region reuse: st+flags overlaps sig (dead after conv1); zqT overlaps h1c (dead after conv2)
  float* sig = ws;                 // 131072 floats (later: h0T/h1T 65536 + flags)
  float* h1c = sig + 131072;       // 4194304  [32][64][2048] (later: zqT, 2097152)
  float* h2c = h1c + 4194304;      // 2097152  [32][64][1024]
  float* ze  = h2c + 2097152;      // 2097152  [32][64][1024]
  float* zq  = ze  + 2097152;      // 2097152  [32*1024][64]
  float* cbn = zq  + 2097152;      // 256
  float* stp = ws;                 // h0T[2][512][32], h1T[2][512][32], flags[256]
  float* zqT = h1c;                // 2097152  [1024][64][32]

  k_mean <<<32768, 256, 0, stream>>>(x, sig);
  k_conv1<<<16384, 256, 0, stream>>>(sig, w1, b1, h1c);
  hipMemsetAsync(stp, 0, (65536 + 1024) * sizeof(float), stream);  // state + flags
  k_conv2<<<8192, 256, 0, stream>>>(h1c, w2, b2, h2c);
  k_conv3<<<8192, 256, 0, stream>>>(h2c, w3, b3, ze);
  k_cbnorm<<<1, 256, 0, stream>>>(cb, cbn);
  k_vq   <<<128, 256, 0, stream>>>(ze, cb, cbn, zq);
  k_zqt  <<<1024, 256, 0, stream>>>(zq, zqT);   // h1c dead now; write zqT over it

  void* kargs[] = { (void*)&zqT, (void*)&wih0, (void*)&whh0, (void*)&bl0,
                    (void*)&wih1, (void*)&whh1, (void*)&bl1,
                    (void*)&wout, (void*)&bout, (void*)&stp, (void*)&out };
  hipLaunchCooperativeKernel((void*)k_lstm, dim3(256), dim3(512), kargs, 0, stream);
}